// Round 9
// baseline (861.517 us; speedup 1.0000x reference)
//
#include <hip/hip_runtime.h>
#include <math.h>

// MultiHeadsGATLayer — algebraic reduction, 2 stream-ordered dispatches.
//   s_src[h][n] = x[n] . (W_heads[h] @ a_src[h]),  s_dst likewise
//   atts = lrelu(s_src[e0]+s_dst[e1]); mt = sum_h atts*lin_w + lin_b
//   out = colwise sparse softmax; non-edge cells underflow to 0 in f32.
// K1: 32 score-blocks (scores, cursor/done zeroing, per-column totals via
//     LDS histogram scan — NO global atomics, so no init race) + 4096 blocks
//     nontemporal zero-stream of the 268MB output.
// K2: fused scatter + completion-triggered softmax: store entry, release
//     fence, done-count; the wave whose lane observed done==total runs the
//     64-lane shuffle-dedup softmax for that column (ballot loop). Direct
//     scattered writes into the pre-zeroed output.
// (R4: grid.sync ~120us/sync on 8-XCD. R7 model: ~14us/dispatch overhead.)

#define ALPHA 0.2f
constexpr int S = 128;
constexpr int O = 64;
constexpr int H = 4;
constexpr int CAP = 128;          // slots per column (degree ~ Poisson(32))
constexpr int SCORE_BLOCKS = 32;  // N / 256

typedef float vf4 __attribute__((ext_vector_type(4)));  // native vec for NT stores

// --- K1: scores + counter init + col totals (no atomics) + NT zero-stream ---
__global__ void __launch_bounds__(256) k1_prep(
    const float* __restrict__ x, const float* __restrict__ W, const float* __restrict__ a,
    const int* __restrict__ edges,
    float4* __restrict__ s_src4, float4* __restrict__ s_dst4,
    int* __restrict__ cursor, int* __restrict__ done, int* __restrict__ total,
    vf4* __restrict__ out4, int N, int E, size_t n4tot)
{
    int tid = threadIdx.x;
    if (blockIdx.x < (unsigned)SCORE_BLOCKS) {
        __shared__ float wsbuf[2 * H * S];
        __shared__ int hist[256];
        // fold W_heads @ a_heads halves -> 2*H*S vector
        for (int t = tid; t < 2 * H * S; t += 256) {
            int which = t / (H * S);           // 0 = src half, 1 = dst half
            int hs = t % (H * S);
            int h = hs / S, s = hs % S;
            const float* Wr = W + ((size_t)h * S + s) * O;
            const float* av = a + h * 2 * O + which * O;
            float acc = 0.f;
            for (int o = 0; o < O; ++o) acc += Wr[o] * av[o];
            wsbuf[t] = acc;
        }
        hist[tid] = 0;
        __syncthreads();
        int n = blockIdx.x * 256 + tid;        // n < N by construction
        cursor[n] = 0;
        done[n] = 0;
        // per-node scores
        {
            const float* wsrc = wsbuf;
            const float* wdst = wsbuf + H * S;
            const float4* xr = (const float4*)(x + (size_t)n * S);
            float accs[H] = {0, 0, 0, 0}, accd[H] = {0, 0, 0, 0};
            for (int i = 0; i < S / 4; ++i) {
                float4 v = xr[i];
#pragma unroll
                for (int h = 0; h < H; ++h) {
                    const float* p = wsrc + h * S + i * 4;
                    const float* q = wdst + h * S + i * 4;
                    accs[h] += v.x * p[0] + v.y * p[1] + v.z * p[2] + v.w * p[3];
                    accd[h] += v.x * q[0] + v.y * q[1] + v.z * q[2] + v.w * q[3];
                }
            }
            s_src4[n] = make_float4(accs[0], accs[1], accs[2], accs[3]);
            s_dst4[n] = make_float4(accd[0], accd[1], accd[2], accd[3]);
        }
        // column totals for owned range via LDS histogram (block-local atomics only)
        int base = blockIdx.x * 256;
        for (int e = tid; e < E; e += 256) {
            int c = edges[(size_t)E + e];
            unsigned rel = (unsigned)(c - base);
            if (rel < 256u) atomicAdd(&hist[rel], 1);
        }
        __syncthreads();
        total[base + tid] = hist[tid];
    } else {
        // nontemporal zero-stream of the output
        const vf4 z4 = {0.f, 0.f, 0.f, 0.f};
        size_t gt = (size_t)(blockIdx.x - SCORE_BLOCKS) * 256 + tid;
        size_t GT = (size_t)(gridDim.x - SCORE_BLOCKS) * 256;
        for (size_t k = gt; k < n4tot; k += GT)
            __builtin_nontemporal_store(z4, &out4[k]);
    }
}

// --- K2: fused edge scatter + completion-triggered per-column softmax ---
__global__ void __launch_bounds__(256) k2_fused(
    const int* __restrict__ edges, const float* __restrict__ values,
    const float4* __restrict__ s_src4, const float4* __restrict__ s_dst4,
    const float* __restrict__ lin_w, const float* __restrict__ lin_b,
    int* __restrict__ cursor, int* __restrict__ done, const int* __restrict__ total,
    int4* __restrict__ col_ent, float* __restrict__ out, int N, int E)
{
    int e = blockIdx.x * 256 + threadIdx.x;
    int lane = threadIdx.x & 63;

    // --- scatter phase (no early returns: all lanes reach the ballot) ---
    int r = 0, c = 0;
    bool valid = false;
    if (e < E) {
        r = edges[e];
        c = edges[(size_t)E + e];
        valid = ((unsigned)r < (unsigned)N) && ((unsigned)c < (unsigned)N);
    }
    if (valid) {
        float4 ss = s_src4[r];
        float4 sd = s_dst4[c];
        float a0 = ss.x + sd.x, a1 = ss.y + sd.y, a2 = ss.z + sd.z, a3 = ss.w + sd.w;
        a0 = a0 >= 0.f ? a0 : ALPHA * a0;
        a1 = a1 >= 0.f ? a1 : ALPHA * a1;
        a2 = a2 >= 0.f ? a2 : ALPHA * a2;
        a3 = a3 >= 0.f ? a3 : ALPHA * a3;
        float mt = lin_b[0] + a0 * lin_w[0] + a1 * lin_w[1] + a2 * lin_w[2] + a3 * lin_w[3];
        float av = values[e];
        float nv = av * mt;
        int posc = atomicAdd(&cursor[c], 1);
        if (posc < CAP) {
            int4 ent;
            ent.x = r;
            ent.y = __float_as_int(nv);
            ent.z = __float_as_int(av);
            ent.w = 0;
            col_ent[(size_t)c * CAP + posc] = ent;
        }
    }
    // release: entry stores globally visible before the done-count
    __threadfence();
    bool complete = false;
    if (valid) {
        int old = atomicAdd(&done[c], 1);
        complete = (old + 1 == total[c]);
    }
    // acquire: before reading other threads' entries
    __threadfence();

    // --- trigger phase: wave handles each column completed by one of its lanes ---
    unsigned long long bal = __ballot(complete);
    while (bal) {
        int b = __ffsll((long long)bal) - 1;
        bal &= bal - 1;
        int cj = __shfl(c, b);
        int mtot = total[cj];
        int m = mtot > CAP ? CAP : mtot;
        const int4* base_p = col_ent + (size_t)cj * CAP;
        if (m <= 64) {
            bool mine = lane < m;
            int rr;
            float vv, aav;
            if (mine) {
                int4 ent = base_p[lane];
                rr = ent.x;
                vv = __int_as_float(ent.y);
                aav = __int_as_float(ent.z);
            } else {
                rr = -1 - lane;   // unique sentinels
                vv = 0.f;
                aav = 0.f;
            }
            float dsum = 0.f, asum = 0.f;
            bool first = true;
            for (int l = 0; l < m; ++l) {
                int rl = __shfl(rr, l);
                float vl = __shfl(vv, l);
                float al = __shfl(aav, l);
                if (rl == rr) {
                    dsum += vl;
                    asum += al;
                    if (l < lane) first = false;
                }
            }
            float mask = (asum == 1.0f) ? 0.f : asum;   // a_dense==1 -> 0, else count
            float val = dsum + mask;
            float lmax = (mine && first) ? val : -INFINITY;
#pragma unroll
            for (int off = 32; off; off >>= 1) lmax = fmaxf(lmax, __shfl_xor(lmax, off));
            float ex = (mine && first) ? expf(val - lmax) : 0.f;   // each group once
            float lsum = ex;
#pragma unroll
            for (int off = 32; off; off >>= 1) lsum += __shfl_xor(lsum, off);
            float inv = 1.0f / lsum;
            // dup group members hold identical val -> idempotent writes
            if (mine) out[(size_t)rr * N + cj] = expf(val - lmax) * inv;
        } else {
            // robust path (column degree > 64; ~never at Poisson(32)) — O(m^2)
            float lmax = -INFINITY;
            for (int k = lane; k < m; k += 64) {
                int rk = base_p[k].x;
                bool first = true;
                float ds = 0.f, as = 0.f;
                for (int l = 0; l < m; ++l) {
                    int4 el = base_p[l];
                    if (el.x == rk) {
                        if (l < k) first = false;
                        ds += __int_as_float(el.y);
                        as += __int_as_float(el.z);
                    }
                }
                if (first) {
                    float mk = (as == 1.0f) ? 0.f : as;
                    lmax = fmaxf(lmax, ds + mk);
                }
            }
#pragma unroll
            for (int off = 32; off; off >>= 1) lmax = fmaxf(lmax, __shfl_xor(lmax, off));
            float lsum = 0.f;
            for (int k = lane; k < m; k += 64) {
                int rk = base_p[k].x;
                bool first = true;
                float ds = 0.f, as = 0.f;
                for (int l = 0; l < m; ++l) {
                    int4 el = base_p[l];
                    if (el.x == rk) {
                        if (l < k) first = false;
                        ds += __int_as_float(el.y);
                        as += __int_as_float(el.z);
                    }
                }
                if (first) {
                    float mk = (as == 1.0f) ? 0.f : as;
                    lsum += expf(ds + mk - lmax);
                }
            }
#pragma unroll
            for (int off = 32; off; off >>= 1) lsum += __shfl_xor(lsum, off);
            float inv = 1.0f / lsum;
            for (int k = lane; k < m; k += 64) {
                int rk = base_p[k].x;
                float ds = 0.f, as = 0.f;
                for (int l = 0; l < m; ++l) {
                    int4 el = base_p[l];
                    if (el.x == rk) {
                        ds += __int_as_float(el.y);
                        as += __int_as_float(el.z);
                    }
                }
                float mk = (as == 1.0f) ? 0.f : as;
                out[(size_t)rk * N + cj] = expf(ds + mk - lmax) * inv;  // idempotent
            }
        }
    }

    // --- empty columns: uniform 1/N (P ~ e^-32 per column; loop ~never runs) ---
    if (e < N && total[e] == 0) {
        float u = 1.0f / (float)N;
        for (int i = 0; i < N; ++i) out[(size_t)i * N + e] = u;
    }
}

extern "C" void kernel_launch(void* const* d_in, const int* in_sizes, int n_in,
                              void* d_out, int out_size, void* d_ws, size_t ws_size,
                              hipStream_t stream) {
    const float* x = (const float*)d_in[0];
    const int* edges = (const int*)d_in[1];      // harness: integer inputs are int32
    const float* values = (const float*)d_in[2];
    const float* W = (const float*)d_in[3];
    const float* a = (const float*)d_in[4];
    const float* lin_w = (const float*)d_in[5];
    const float* lin_b = (const float*)d_in[6];
    float* out = (float*)d_out;

    int N = in_sizes[0] / S;   // 8192
    int E = in_sizes[2];       // 262144

    // workspace carve (256B-aligned slabs)
    char* wsb = (char*)d_ws;
    size_t off = 0;
    auto alloc = [&](size_t bytes) -> void* {
        void* p = wsb + off;
        off += (bytes + 255) & ~(size_t)255;
        return p;
    };
    float4* s_src4 = (float4*)alloc((size_t)N * 16);
    float4* s_dst4 = (float4*)alloc((size_t)N * 16);
    int* cursor = (int*)alloc((size_t)N * 4);
    int* done = (int*)alloc((size_t)N * 4);
    int* total = (int*)alloc((size_t)N * 4);
    int4* col_ent = (int4*)alloc((size_t)N * CAP * 16);

    size_t n4tot = (size_t)N * N / 4;
    int zero_blocks = 4096;
    k1_prep<<<SCORE_BLOCKS + zero_blocks, 256, 0, stream>>>(
        x, W, a, edges, s_src4, s_dst4, cursor, done, total,
        (vf4*)out, N, E, n4tot);
    k2_fused<<<(E + 255) / 256, 256, 0, stream>>>(
        edges, values, s_src4, s_dst4, lin_w, lin_b,
        cursor, done, total, col_ent, out, N, E);
}

// Round 10
// 395.993 us; speedup vs baseline: 2.1756x; 2.1756x over previous
//
#include <hip/hip_runtime.h>
#include <math.h>

// MultiHeadsGATLayer — algebraic reduction, 2 stream-ordered dispatches,
// ZERO inter-block protocols (R4/R9 lesson: fences/grid-sync across the
// 8 non-coherent XCD L2s cost 100x a kernel boundary).
//   s_src[h][n] = x[n] . (W_heads[h] @ a_src[h]),  s_dst likewise
//   atts = lrelu(s_src[e0]+s_dst[e1]); mt = sum_h atts*lin_w + lin_b
//   out = colwise sparse softmax; non-edge cells underflow to 0 in f32.
// K1: 32 score-blocks + 4096 NT-zero-stream blocks (268MB output).
// K2: 256 blocks; block b OWNS columns [32b,32b+32). Each block scans the
//     full dst array (1MB, L2-resident), builds LDS edge lists for its
//     columns, then per-wave shuffle-dedup softmax + direct scattered writes.
//     Completeness by construction — no atomics, no fences.

#define ALPHA 0.2f
constexpr int S = 128;
constexpr int O = 64;
constexpr int H = 4;
constexpr int CAP = 128;          // slots per column (degree ~ Poisson(32))
constexpr int CPB = 32;           // columns per K2 block
constexpr int SCORE_BLOCKS = 32;  // ceil(N/256)

typedef float vf4 __attribute__((ext_vector_type(4)));  // native vec for NT stores

// --- K1: per-node scores + NT zero-stream of the output ---
__global__ void __launch_bounds__(256) k1_prep(
    const float* __restrict__ x, const float* __restrict__ W, const float* __restrict__ a,
    float4* __restrict__ s_src4, float4* __restrict__ s_dst4,
    vf4* __restrict__ out4, int N, size_t n4tot)
{
    int tid = threadIdx.x;
    if (blockIdx.x < (unsigned)SCORE_BLOCKS) {
        __shared__ float wsbuf[2 * H * S];
        for (int t = tid; t < 2 * H * S; t += 256) {
            int which = t / (H * S);           // 0 = src half, 1 = dst half
            int hs = t % (H * S);
            int h = hs / S, s = hs % S;
            const float* Wr = W + ((size_t)h * S + s) * O;
            const float* av = a + h * 2 * O + which * O;
            float acc = 0.f;
            for (int o = 0; o < O; ++o) acc += Wr[o] * av[o];
            wsbuf[t] = acc;
        }
        __syncthreads();
        int n = blockIdx.x * 256 + tid;
        if (n < N) {
            const float* wsrc = wsbuf;
            const float* wdst = wsbuf + H * S;
            const float4* xr = (const float4*)(x + (size_t)n * S);
            float accs[H] = {0, 0, 0, 0}, accd[H] = {0, 0, 0, 0};
            for (int i = 0; i < S / 4; ++i) {
                float4 v = xr[i];
#pragma unroll
                for (int h = 0; h < H; ++h) {
                    const float* p = wsrc + h * S + i * 4;
                    const float* q = wdst + h * S + i * 4;
                    accs[h] += v.x * p[0] + v.y * p[1] + v.z * p[2] + v.w * p[3];
                    accd[h] += v.x * q[0] + v.y * q[1] + v.z * q[2] + v.w * q[3];
                }
            }
            s_src4[n] = make_float4(accs[0], accs[1], accs[2], accs[3]);
            s_dst4[n] = make_float4(accd[0], accd[1], accd[2], accd[3]);
        }
    } else {
        const vf4 z4 = {0.f, 0.f, 0.f, 0.f};
        size_t gt = (size_t)(blockIdx.x - SCORE_BLOCKS) * 256 + tid;
        size_t GT = (size_t)(gridDim.x - SCORE_BLOCKS) * 256;
        for (size_t k = gt; k < n4tot; k += GT)
            __builtin_nontemporal_store(z4, &out4[k]);
    }
}

// --- K2: block-exclusive column ownership; LDS lists; shuffle-dedup softmax ---
__global__ void __launch_bounds__(256) k2_colblock(
    const int* __restrict__ edges, const float* __restrict__ values,
    const float4* __restrict__ s_src4, const float4* __restrict__ s_dst4,
    const float* __restrict__ lin_w, const float* __restrict__ lin_b,
    float* __restrict__ out, int N, int E)
{
    __shared__ int cnt[CPB];
    __shared__ int lr[CPB][CAP];      // row index
    __shared__ float lnv[CPB][CAP];   // new value
    __shared__ float lav[CPB][CAP];   // original a-value
    int tid = threadIdx.x;
    int base = blockIdx.x * CPB;

    for (int i = tid; i < CPB; i += 256) cnt[i] = 0;
    __syncthreads();

    // scan all edges; keep those whose dst column is owned
    float lw0 = lin_w[0], lw1 = lin_w[1], lw2 = lin_w[2], lw3 = lin_w[3];
    float lb = lin_b[0];
    for (int e = tid; e < E; e += 256) {
        int c = edges[(size_t)E + e];
        unsigned rel = (unsigned)(c - base);
        if (rel < (unsigned)CPB) {
            int r = edges[e];
            if ((unsigned)r < (unsigned)N) {
                float4 ss = s_src4[r];
                float4 sd = s_dst4[c];
                float a0 = ss.x + sd.x, a1 = ss.y + sd.y;
                float a2 = ss.z + sd.z, a3 = ss.w + sd.w;
                a0 = a0 >= 0.f ? a0 : ALPHA * a0;
                a1 = a1 >= 0.f ? a1 : ALPHA * a1;
                a2 = a2 >= 0.f ? a2 : ALPHA * a2;
                a3 = a3 >= 0.f ? a3 : ALPHA * a3;
                float mt = lb + a0 * lw0 + a1 * lw1 + a2 * lw2 + a3 * lw3;
                float av = values[e];
                int pos = atomicAdd(&cnt[rel], 1);   // LDS atomic (block-local)
                if (pos < CAP) {
                    lr[rel][pos] = r;
                    lnv[rel][pos] = av * mt;
                    lav[rel][pos] = av;
                }
            }
        }
    }
    __syncthreads();

    // per-wave softmax over owned columns
    int wave = tid >> 6, lane = tid & 63;
    for (int q = wave; q < CPB; q += 4) {
        int j = base + q;
        if (j >= N) continue;
        int m = cnt[q];
        if (m > CAP) m = CAP;
        if (m == 0) {
            // empty column (P ~ e^-32): uniform softmax
            float u = 1.0f / (float)N;
            for (int i = lane; i < N; i += 64) out[(size_t)i * N + j] = u;
            continue;
        }
        if (m <= 64) {
            bool mine = lane < m;
            int rr;
            float vv, aav;
            if (mine) {
                rr = lr[q][lane];
                vv = lnv[q][lane];
                aav = lav[q][lane];
            } else {
                rr = -1 - lane;   // unique sentinels
                vv = 0.f;
                aav = 0.f;
            }
            float dsum = 0.f, asum = 0.f;
            bool first = true;
            for (int l = 0; l < m; ++l) {
                int rl = __shfl(rr, l);
                float vl = __shfl(vv, l);
                float al = __shfl(aav, l);
                if (rl == rr) {
                    dsum += vl;
                    asum += al;
                    if (l < lane) first = false;
                }
            }
            float mask = (asum == 1.0f) ? 0.f : asum;   // a_dense==1 -> 0, else count
            float val = dsum + mask;
            float lmax = (mine && first) ? val : -INFINITY;
#pragma unroll
            for (int off = 32; off; off >>= 1) lmax = fmaxf(lmax, __shfl_xor(lmax, off));
            float ex = (mine && first) ? expf(val - lmax) : 0.f;   // each group once
            float lsum = ex;
#pragma unroll
            for (int off = 32; off; off >>= 1) lsum += __shfl_xor(lsum, off);
            float inv = 1.0f / lsum;
            // dup group members hold identical val -> idempotent writes
            if (mine) out[(size_t)rr * N + j] = expf(val - lmax) * inv;
        } else {
            // robust path (64 < degree <= CAP) — O(m^2) over LDS lists
            float lmax = -INFINITY;
            for (int k = lane; k < m; k += 64) {
                int rk = lr[q][k];
                bool first = true;
                float ds = 0.f, as = 0.f;
                for (int l = 0; l < m; ++l) {
                    if (lr[q][l] == rk) {
                        if (l < k) first = false;
                        ds += lnv[q][l];
                        as += lav[q][l];
                    }
                }
                if (first) {
                    float mk = (as == 1.0f) ? 0.f : as;
                    lmax = fmaxf(lmax, ds + mk);
                }
            }
#pragma unroll
            for (int off = 32; off; off >>= 1) lmax = fmaxf(lmax, __shfl_xor(lmax, off));
            float lsum = 0.f;
            for (int k = lane; k < m; k += 64) {
                int rk = lr[q][k];
                bool first = true;
                float ds = 0.f, as = 0.f;
                for (int l = 0; l < m; ++l) {
                    if (lr[q][l] == rk) {
                        if (l < k) first = false;
                        ds += lnv[q][l];
                        as += lav[q][l];
                    }
                }
                if (first) {
                    float mk = (as == 1.0f) ? 0.f : as;
                    lsum += expf(ds + mk - lmax);
                }
            }
#pragma unroll
            for (int off = 32; off; off >>= 1) lsum += __shfl_xor(lsum, off);
            float inv = 1.0f / lsum;
            for (int k = lane; k < m; k += 64) {
                int rk = lr[q][k];
                float ds = 0.f, as = 0.f;
                for (int l = 0; l < m; ++l) {
                    if (lr[q][l] == rk) {
                        ds += lnv[q][l];
                        as += lav[q][l];
                    }
                }
                float mk = (as == 1.0f) ? 0.f : as;
                out[(size_t)rk * N + j] = expf(ds + mk - lmax) * inv;  // idempotent
            }
        }
    }
}

extern "C" void kernel_launch(void* const* d_in, const int* in_sizes, int n_in,
                              void* d_out, int out_size, void* d_ws, size_t ws_size,
                              hipStream_t stream) {
    const float* x = (const float*)d_in[0];
    const int* edges = (const int*)d_in[1];      // harness: integer inputs are int32
    const float* values = (const float*)d_in[2];
    const float* W = (const float*)d_in[3];
    const float* a = (const float*)d_in[4];
    const float* lin_w = (const float*)d_in[5];
    const float* lin_b = (const float*)d_in[6];
    float* out = (float*)d_out;

    int N = in_sizes[0] / S;   // 8192
    int E = in_sizes[2];       // 262144

    // workspace carve (256B-aligned slabs)
    char* wsb = (char*)d_ws;
    size_t off = 0;
    auto alloc = [&](size_t bytes) -> void* {
        void* p = wsb + off;
        off += (bytes + 255) & ~(size_t)255;
        return p;
    };
    float4* s_src4 = (float4*)alloc((size_t)N * 16);
    float4* s_dst4 = (float4*)alloc((size_t)N * 16);

    size_t n4tot = (size_t)N * N / 4;
    k1_prep<<<SCORE_BLOCKS + 4096, 256, 0, stream>>>(
        x, W, a, s_src4, s_dst4, (vf4*)out, N, n4tot);
    k2_colblock<<<(N + CPB - 1) / CPB, 256, 0, stream>>>(
        edges, values, s_src4, s_dst4, lin_w, lin_b, out, N, E);
}

// Round 11
// 142.783 us; speedup vs baseline: 6.0337x; 2.7734x over previous
//
#include <hip/hip_runtime.h>
#include <math.h>

// MultiHeadsGATLayer — algebraic reduction, 2 dispatches, write-once output.
//   s_src[h][n] = x[n] . (W_heads[h] @ a_src[h]),  s_dst likewise
//   atts = lrelu(s_src[e0]+s_dst[e1]); mt = sum_h atts*lin_w + lin_b
//   out = colwise sparse softmax; non-edge cells exactly 0 (f32 underflow).
// K1: per-node scores (tiny). K2: block owns 32 columns — int4 dst scan
// (64 indep loads/thread, 16 waves/CU: fixes R10's 1-wave/SIMD latency trap),
// LDS binning, shuffle-dedup softmax, then 512x32 LDS tile chunks streamed
// with NT float4 stores. No zero pass, no cursors, no global atomics/fences
// (R4/R9: cross-XCD protocols ~100x a kernel boundary).

#define ALPHA 0.2f
constexpr int S = 128;
constexpr int O = 64;
constexpr int H = 4;
constexpr int CAP = 128;    // slots per column (degree ~ Poisson(32))
constexpr int CPB = 32;     // columns per K2 block
constexpr int CHUNK = 512;  // rows per LDS tile chunk
constexpr int TPB = 1024;   // K2 threads per block

typedef float vf4 __attribute__((ext_vector_type(4)));

// --- K1: per-node scores (head-major float4) ---
__global__ void __launch_bounds__(256) k1_scores(
    const float* __restrict__ x, const float* __restrict__ W, const float* __restrict__ a,
    float4* __restrict__ s_src4, float4* __restrict__ s_dst4, int N)
{
    __shared__ float wsbuf[2 * H * S];
    int tid = threadIdx.x;
    for (int t = tid; t < 2 * H * S; t += 256) {
        int which = t / (H * S);           // 0 = src half, 1 = dst half
        int hs = t % (H * S);
        int h = hs / S, s = hs % S;
        const float* Wr = W + ((size_t)h * S + s) * O;
        const float* av = a + h * 2 * O + which * O;
        float acc = 0.f;
        for (int o = 0; o < O; ++o) acc += Wr[o] * av[o];
        wsbuf[t] = acc;
    }
    __syncthreads();
    int n = blockIdx.x * 256 + tid;
    if (n >= N) return;
    const float* wsrc = wsbuf;
    const float* wdst = wsbuf + H * S;
    const float4* xr = (const float4*)(x + (size_t)n * S);
    float accs[H] = {0, 0, 0, 0}, accd[H] = {0, 0, 0, 0};
    for (int i = 0; i < S / 4; ++i) {
        float4 v = xr[i];
#pragma unroll
        for (int h = 0; h < H; ++h) {
            const float* p = wsrc + h * S + i * 4;
            const float* q = wdst + h * S + i * 4;
            accs[h] += v.x * p[0] + v.y * p[1] + v.z * p[2] + v.w * p[3];
            accd[h] += v.x * q[0] + v.y * q[1] + v.z * q[2] + v.w * q[3];
        }
    }
    s_src4[n] = make_float4(accs[0], accs[1], accs[2], accs[3]);
    s_dst4[n] = make_float4(accd[0], accd[1], accd[2], accd[3]);
}

// --- K2: fused bin-scan + softmax + tiled coalesced write ---
__global__ void __launch_bounds__(TPB) k2_all(
    const int* __restrict__ edges, const float* __restrict__ values,
    const float4* __restrict__ s_src4, const float4* __restrict__ s_dst4,
    const float* __restrict__ lin_w, const float* __restrict__ lin_b,
    float* __restrict__ out, int N, int E)
{
    __shared__ int cnt[CPB];
    __shared__ int lr[CPB][CAP];
    __shared__ float lnv[CPB][CAP];
    __shared__ float lav[CPB][CAP];
    __shared__ float lfin[CPB][CAP];
    __shared__ float initval[CPB];
    __shared__ float tile[CHUNK * CPB];   // 64 KB

    int tid = threadIdx.x;
    int c0 = blockIdx.x * CPB;
    if (tid < CPB) cnt[tid] = 0;
    __syncthreads();

    float lw0 = lin_w[0], lw1 = lin_w[1], lw2 = lin_w[2], lw3 = lin_w[3];
    float lb = lin_b[0];

    // --- phase B: int4 scan of dst; bin owned edges with logits ---
    const int* dst = edges + (size_t)E;
    auto process = [&](int c, int e) {
        unsigned rel = (unsigned)(c - c0);
        if (rel < (unsigned)CPB) {
            int r = edges[e];
            if ((unsigned)r < (unsigned)N) {
                float4 ss = s_src4[r];
                float4 sd = s_dst4[c];
                float a0 = ss.x + sd.x, a1 = ss.y + sd.y;
                float a2 = ss.z + sd.z, a3 = ss.w + sd.w;
                a0 = a0 >= 0.f ? a0 : ALPHA * a0;
                a1 = a1 >= 0.f ? a1 : ALPHA * a1;
                a2 = a2 >= 0.f ? a2 : ALPHA * a2;
                a3 = a3 >= 0.f ? a3 : ALPHA * a3;
                float mt = lb + a0 * lw0 + a1 * lw1 + a2 * lw2 + a3 * lw3;
                float av = values[e];
                int pos = atomicAdd(&cnt[rel], 1);   // LDS atomic
                if (pos < CAP) {
                    lr[rel][pos] = r;
                    lnv[rel][pos] = av * mt;
                    lav[rel][pos] = av;
                }
            }
        }
    };
    int nq = E >> 2;
    const int4* dst4 = (const int4*)dst;
    for (int i = tid; i < nq; i += TPB) {
        int4 q = dst4[i];
        int e = i << 2;
        process(q.x, e);
        process(q.y, e + 1);
        process(q.z, e + 2);
        process(q.w, e + 3);
    }
    for (int e = (nq << 2) + tid; e < E; e += TPB) process(dst[e], e);
    __syncthreads();

    // --- phase C: per-column softmax (16 waves x 2 cols) -> lfin ---
    int wave = tid >> 6, lane = tid & 63;
    for (int q = wave; q < CPB; q += TPB / 64) {
        int m = cnt[q];
        if (m > CAP) m = CAP;
        if (lane == 0) initval[q] = (m == 0) ? (1.0f / (float)N) : 0.f;
        if (m == 0) continue;
        if (m <= 64) {
            bool mine = lane < m;
            int rr;
            float vv, aav;
            if (mine) {
                rr = lr[q][lane];
                vv = lnv[q][lane];
                aav = lav[q][lane];
            } else {
                rr = -1 - lane;   // unique sentinels
                vv = 0.f;
                aav = 0.f;
            }
            float dsum = 0.f, asum = 0.f;
            bool first = true;
            for (int l = 0; l < m; ++l) {
                int rl = __shfl(rr, l);
                float vl = __shfl(vv, l);
                float al = __shfl(aav, l);
                if (rl == rr) {
                    dsum += vl;
                    asum += al;
                    if (l < lane) first = false;
                }
            }
            float mask = (asum == 1.0f) ? 0.f : asum;   // a_dense==1 -> 0, else count
            float val = dsum + mask;
            float lmax = (mine && first) ? val : -INFINITY;
#pragma unroll
            for (int off = 32; off; off >>= 1) lmax = fmaxf(lmax, __shfl_xor(lmax, off));
            float ex = (mine && first) ? expf(val - lmax) : 0.f;   // each group once
            float lsum = ex;
#pragma unroll
            for (int off = 32; off; off >>= 1) lsum += __shfl_xor(lsum, off);
            float inv = 1.0f / lsum;
            // dup group members hold identical val -> idempotent
            if (mine) lfin[q][lane] = expf(val - lmax) * inv;
        } else {
            // robust path (64 < m <= CAP): O(m^2), finals into regs then lfin
            float lmax = -INFINITY;
            for (int k = lane; k < m; k += 64) {
                int rk = lr[q][k];
                bool first = true;
                float ds = 0.f, as = 0.f;
                for (int l = 0; l < m; ++l) {
                    if (lr[q][l] == rk) {
                        if (l < k) first = false;
                        ds += lnv[q][l];
                        as += lav[q][l];
                    }
                }
                if (first) {
                    float mk = (as == 1.0f) ? 0.f : as;
                    lmax = fmaxf(lmax, ds + mk);
                }
            }
#pragma unroll
            for (int off = 32; off; off >>= 1) lmax = fmaxf(lmax, __shfl_xor(lmax, off));
            float lsum = 0.f;
            for (int k = lane; k < m; k += 64) {
                int rk = lr[q][k];
                bool first = true;
                float ds = 0.f, as = 0.f;
                for (int l = 0; l < m; ++l) {
                    if (lr[q][l] == rk) {
                        if (l < k) first = false;
                        ds += lnv[q][l];
                        as += lav[q][l];
                    }
                }
                if (first) {
                    float mk = (as == 1.0f) ? 0.f : as;
                    lsum += expf(ds + mk - lmax);
                }
            }
#pragma unroll
            for (int off = 32; off; off >>= 1) lsum += __shfl_xor(lsum, off);
            float inv = 1.0f / lsum;
            for (int k = lane; k < m; k += 64) {
                int rk = lr[q][k];
                float ds = 0.f, as = 0.f;
                for (int l = 0; l < m; ++l) {
                    if (lr[q][l] == rk) {
                        ds += lnv[q][l];
                        as += lav[q][l];
                    }
                }
                float mk = (as == 1.0f) ? 0.f : as;
                lfin[q][k] = expf(ds + mk - lmax) * inv;   // idempotent for dups
            }
        }
    }
    __syncthreads();

    // --- phase D: chunked tile compose + NT coalesced stream ---
    int nch = (N + CHUNK - 1) / CHUNK;
    vf4* t4 = (vf4*)tile;
    const int NF4 = CHUNK * CPB / 4;   // 4096
    for (int ch = 0; ch < nch; ++ch) {
        int r0 = ch * CHUNK;
        for (int p = tid; p < NF4; p += TPB) {
            int cg = (p & 7) << 2;
            vf4 v = {initval[cg], initval[cg + 1], initval[cg + 2], initval[cg + 3]};
            t4[p] = v;
        }
        __syncthreads();
        for (int s = tid; s < CPB * CAP; s += TPB) {
            int col = s >> 7, slot = s & (CAP - 1);
            int m = cnt[col];
            if (m > CAP) m = CAP;
            if (slot < m) {
                int rr = lr[col][slot] - r0;
                if ((unsigned)rr < (unsigned)CHUNK) tile[rr * CPB + col] = lfin[col][slot];
            }
        }
        __syncthreads();
        for (int p = tid; p < NF4; p += TPB) {
            int row = p >> 3, f4c = p & 7;
            int grow = r0 + row;
            if (grow < N) {
                vf4 v = t4[p];
                __builtin_nontemporal_store(v, (vf4*)(out + (size_t)grow * N + c0) + f4c);
            }
        }
        __syncthreads();
    }
}

extern "C" void kernel_launch(void* const* d_in, const int* in_sizes, int n_in,
                              void* d_out, int out_size, void* d_ws, size_t ws_size,
                              hipStream_t stream) {
    const float* x = (const float*)d_in[0];
    const int* edges = (const int*)d_in[1];      // harness: integer inputs are int32
    const float* values = (const float*)d_in[2];
    const float* W = (const float*)d_in[3];
    const float* a = (const float*)d_in[4];
    const float* lin_w = (const float*)d_in[5];
    const float* lin_b = (const float*)d_in[6];
    float* out = (float*)d_out;

    int N = in_sizes[0] / S;   // 8192
    int E = in_sizes[2];       // 262144

    // workspace carve (256B-aligned slabs)
    char* wsb = (char*)d_ws;
    size_t off = 0;
    auto alloc = [&](size_t bytes) -> void* {
        void* p = wsb + off;
        off += (bytes + 255) & ~(size_t)255;
        return p;
    };
    float4* s_src4 = (float4*)alloc((size_t)N * 16);
    float4* s_dst4 = (float4*)alloc((size_t)N * 16);

    k1_scores<<<(N + 255) / 256, 256, 0, stream>>>(x, W, a, s_src4, s_dst4, N);
    k2_all<<<(N + CPB - 1) / CPB, TPB, 0, stream>>>(edges, values, s_src4, s_dst4,
                                                    lin_w, lin_b, out, N, E);
}